// Round 2
// baseline (71.509 us; speedup 1.0000x reference)
//
#include <hip/hip_runtime.h>
#include <hip/hip_bf16.h>

// Problem constants (match the reference's trie layout)
#define V_SZ   32768          // vocab
#define C_CH   32             // children per unigram
#define G_SZ   V_SZ           // unigram log-prob count
#define U_OFF  (V_SZ + 1)     // first bigram node index
#define K_SZ   (V_SZ * C_CH)  // bigram node count
#define X_SZ   (K_SZ + 1)     // pointers length
#define B_SZ   32             // batch
#define CHUNK  4096           // V-elements per block
#define NCHUNK (V_SZ / CHUNK) // 8 blocks along V per batch row
#define ITER   4              // float4s per thread (4 * 4 * 256 = 4096)

// One block per (batch b, 4096-wide V-chunk). 256 threads, 16 fp32/thread as
// 4 independent float4 load-add-store chains (ILP to hide L2/HBM latency).
// Phase 1: coalesced fill out[b, v] = backoff[h_b] + logs[v].
// Phase 2 (after barrier): lanes 0..31 check the 32 children of h_b; if a
// child's token falls inside THIS block's chunk, overwrite with the bigram lp.
// The same block wrote the default at that address, and __syncthreads implies
// s_waitcnt vmcnt(0) before s_barrier, so the store order is guaranteed.
__global__ __launch_bounds__(256) void lookup_lm_kernel(
    const int* __restrict__ hist,      // (S, B)
    const int* __restrict__ idx_p,     // scalar
    const int* __restrict__ pointers,  // (X)
    const int* __restrict__ ids,       // (K)
    const float* __restrict__ logs,    // (L = 2X + G)
    float* __restrict__ out)           // (B, V)
{
    const int b     = blockIdx.y;
    const int chunk = blockIdx.x;
    const int s     = idx_p[0];

    const int h   = hist[(s - 1) * B_SZ + b];       // last context token (uniform/block)
    const float backoff = logs[X_SZ + G_SZ + h];    // unigram backoff weight

    // ---- Phase 1: dense backoff fill (4 independent coalesced float4 ops) ----
    const int lo = chunk * CHUNK;
    const int v0 = lo + threadIdx.x * 4;
    float4 lg[ITER];
#pragma unroll
    for (int k = 0; k < ITER; ++k)
        lg[k] = *reinterpret_cast<const float4*>(logs + v0 + k * 1024);
#pragma unroll
    for (int k = 0; k < ITER; ++k) {
        float4 o;
        o.x = backoff + lg[k].x;
        o.y = backoff + lg[k].y;
        o.z = backoff + lg[k].z;
        o.w = backoff + lg[k].w;
        *reinterpret_cast<float4*>(out + b * V_SZ + v0 + k * 1024) = o;
    }

    __syncthreads();   // fill visible before override (vmcnt drain + barrier)

    // ---- Phase 2: sparse bigram override ----
    const int j = threadIdx.x;
    if (j < C_CH) {
        const int off = pointers[h];
        const int nc  = pointers[h + 1] - off + 1;  // num children
        if (j < nc) {
            const int node = h + off + j;           // bigram node id
            const int tok  = ids[node - U_OFF];
            if (tok >= lo && tok < lo + CHUNK) {
                out[b * V_SZ + tok] = logs[node];
            }
        }
    }
}

extern "C" void kernel_launch(void* const* d_in, const int* in_sizes, int n_in,
                              void* d_out, int out_size, void* d_ws, size_t ws_size,
                              hipStream_t stream) {
    const int*   hist     = (const int*)d_in[0];
    const int*   idx_p    = (const int*)d_in[1];
    const int*   pointers = (const int*)d_in[2];
    const int*   ids      = (const int*)d_in[3];
    const float* logs     = (const float*)d_in[4];
    float*       out      = (float*)d_out;

    dim3 grid(NCHUNK, B_SZ);   // 8 x 32 = 256 blocks (one per CU)
    dim3 block(256);
    lookup_lm_kernel<<<grid, block, 0, stream>>>(hist, idx_p, pointers, ids, logs, out);
}